// Round 5
// baseline (177.199 us; speedup 1.0000x reference)
//
#include <hip/hip_runtime.h>
#include <hip/hip_bf16.h>
#include <math.h>

constexpr int Bsz   = 1024;
constexpr int S     = 512;
constexpr int SV    = 511;   // attention rows (all but last)
constexpr int D     = 32;
constexpr int F     = 4;
constexpr int H     = 64;
constexpr int BDIM  = 256;
constexpr int VOCAB = 100001;
constexpr size_t TAB_BYTES = (size_t)VOCAB * 64 * 2;   // bf16 table

__device__ __forceinline__ float fast_tanh(float x) {
  // tanh(x) = 1 - 2/(e^{2x}+1); exp overflow -> inf -> rcp -> 0 -> 1 (correct limit)
  const float ex = __expf(2.f * x);
  return 1.f - 2.f * __builtin_amdgcn_rcpf(ex + 1.f);
}

__device__ __forceinline__ void unpack8(uint4 u, float* f) {
  // 8 bf16 (little-endian packed) -> 8 f32 via bit shifts (no cvt ops)
  f[0] = __uint_as_float(u.x << 16); f[1] = __uint_as_float(u.x & 0xffff0000u);
  f[2] = __uint_as_float(u.y << 16); f[3] = __uint_as_float(u.y & 0xffff0000u);
  f[4] = __uint_as_float(u.z << 16); f[5] = __uint_as_float(u.z & 0xffff0000u);
  f[6] = __uint_as_float(u.w << 16); f[7] = __uint_as_float(u.w & 0xffff0000u);
}

// ---- build: T16[VOCAB][64] = bf16[ emb_row | emb_row @ Wv ];  last block: W2T/bias2 ----
__global__ __launch_bounds__(BDIM) void build_tab(
    const float* __restrict__ emb, const float* __restrict__ Wv,
    const float* __restrict__ W_num, const float* __restrict__ b_num,
    const float* __restrict__ bv,
    __hip_bfloat16* __restrict__ T, float* __restrict__ wsc)
{
  __shared__ float sWv[D * D];
  for (int i = threadIdx.x; i < D * D; i += BDIM) sWv[i] = Wv[i];
  __syncthreads();

  if (blockIdx.x == gridDim.x - 1) {
    const int tid = threadIdx.x;
    if (tid < F * D) {                     // W2[f][k] stored transposed: wsc[k*4+f]
      const int f = tid >> 5, k = tid & 31;
      float a = 0.f;
      #pragma unroll
      for (int m = 0; m < D; m++) a += W_num[f * D + m] * sWv[m * D + k];
      wsc[k * 4 + f] = a;
    } else if (tid < F * D + D) {          // bias2[k] = bv + b_num@Wv at wsc[128+k]
      const int k = tid - F * D;
      float a = bv[k];
      #pragma unroll
      for (int m = 0; m < D; m++) a += b_num[m] * sWv[m * D + k];
      wsc[F * D + k] = a;
    }
    return;
  }

  const int lr = threadIdx.x >> 5, k = threadIdx.x & 31;
  const int row = blockIdx.x * 8 + lr;
  if (row < VOCAB) {
    const float4* e4 = reinterpret_cast<const float4*>(emb + (size_t)row * D);
    float a = 0.f;
    #pragma unroll
    for (int c = 0; c < 8; c++) {
      const float4 v = e4[c];
      a += v.x * sWv[(4 * c + 0) * D + k] + v.y * sWv[(4 * c + 1) * D + k]
         + v.z * sWv[(4 * c + 2) * D + k] + v.w * sWv[(4 * c + 3) * D + k];
    }
    T[(size_t)row * 64 + k]      = __float2bfloat16(emb[(size_t)row * D + k]);
    T[(size_t)row * 64 + 32 + k] = __float2bfloat16(a);
  }
}

// ================= main fused kernel (bf16 table path) =================
__global__ __launch_bounds__(BDIM) void attn_main(
    const float* __restrict__ values, const int* __restrict__ names,
    const __hip_bfloat16* __restrict__ T, const float* __restrict__ wsc,
    const float* __restrict__ emb,
    const float* __restrict__ W_num, const float* __restrict__ b_num,
    const float* __restrict__ Wq,    const float* __restrict__ bq,
    const float* __restrict__ attn_scale,
    const float* __restrict__ Wp,    const float* __restrict__ bp,
    const float* __restrict__ ln_g,  const float* __restrict__ ln_b,
    const float* __restrict__ Ws,
    float* __restrict__ out_score, float* __restrict__ out_emb,
    float* __restrict__ out_attn,  float* __restrict__ out_h)
{
  __shared__ float sW2T[D][4];   // W2 transposed: [k][f]
  __shared__ float sQS[D][2];    // {q+bias2, scale}
  __shared__ float smixq[D];
  __shared__ float sred[4][69];  // per wave: acc[32], esum[32], lloc, vsum[4]
  __shared__ float sctx[D];
  __shared__ float sL[1];

  const int b = blockIdx.x, tid = threadIdx.x, lane = tid & 63, wv = tid >> 6;

  if (tid < 128) sW2T[tid >> 2][tid & 3] = wsc[tid];
  if (tid < D) {
    const int    nq = names[b * S + (S - 1)];
    const float* vr = values + (size_t)(b * S + (S - 1)) * F;
    smixq[tid] = emb[(size_t)nq * D + tid] + b_num[tid]
               + vr[0] * W_num[tid] + vr[1] * W_num[D + tid]
               + vr[2] * W_num[2 * D + tid] + vr[3] * W_num[3 * D + tid];
  }
  __syncthreads();
  if (tid < D) {
    float a = bq[tid];
    #pragma unroll
    for (int m = 0; m < D; m++) a += smixq[m] * Wq[m * D + tid];
    sQS[tid][0] = a + wsc[128 + tid];   // q + bias2
    sQS[tid][1] = attn_scale[tid];
  }
  __syncthreads();

  // ---- stage both rows' data (MLP), then compute ----
  const int  j0 = tid, j1 = tid + BDIM;
  const bool has1 = (j1 < SV);                 // tid < 255
  const int  n0 = names[b * S + j0];
  const int  n1 = names[b * S + (has1 ? j1 : j0)];
  float4 v0 = *reinterpret_cast<const float4*>(values + (size_t)(b * S + j0) * F);
  float4 v1 = *reinterpret_cast<const float4*>(values + (size_t)(b * S + (has1 ? j1 : j0)) * F);
  const uint4* g0 = reinterpret_cast<const uint4*>(T + (size_t)n0 * 64);
  const uint4* g1 = reinterpret_cast<const uint4*>(T + (size_t)n1 * 64);
  uint4 E00 = g0[0], E01 = g0[1], E02 = g0[2], E03 = g0[3];
  uint4 W00 = g0[4], W01 = g0[5], W02 = g0[6], W03 = g0[7];
  uint4 E10 = g1[0], E11 = g1[1], E12 = g1[2], E13 = g1[3];
  uint4 W10 = g1[4], W11 = g1[5], W12 = g1[6], W13 = g1[7];

  float esum[D], acc[D];
  #pragma unroll
  for (int k = 0; k < D; k++) { esum[k] = 0.f; acc[k] = 0.f; }
  float lloc = 0.f, e0 = 0.f, e1 = 0.f;
  float vs0 = v0.x, vs1 = v0.y, vs2 = v0.z, vs3 = v0.w;
  if (has1) { vs0 += v1.x; vs1 += v1.y; vs2 += v1.z; vs3 += v1.w; }

  auto dorow = [&](uint4 Ea, uint4 Eb, uint4 Ec, uint4 Ed,
                   uint4 Wa, uint4 Wb, uint4 Wc, uint4 Wd, float4 vv) -> float {
    float em[D], w[D], t[D];
    unpack8(Ea, em); unpack8(Eb, em + 8); unpack8(Ec, em + 16); unpack8(Ed, em + 24);
    unpack8(Wa, w);  unpack8(Wb, w + 8);  unpack8(Wc, w + 16);  unpack8(Wd, w + 24);
    float s = 0.f;
    #pragma unroll
    for (int k = 0; k < D; k++) {
      esum[k] += em[k];
      const float tk = w[k] + sQS[k][0]
                     + vv.x * sW2T[k][0] + vv.y * sW2T[k][1]
                     + vv.z * sW2T[k][2] + vv.w * sW2T[k][3];   // t = q + val
      t[k] = tk;
      s += sQS[k][1] * fast_tanh(tk);
    }
    const float e = __expf(s);          // |s| <= sum|scale| = 32 -> no overflow
    lloc += e;
    #pragma unroll
    for (int k = 0; k < D; k++) acc[k] = fmaf(e, t[k], acc[k]);
    return e;
  };

  e0 = dorow(E00, E01, E02, E03, W00, W01, W02, W03, v0);
  if (has1) e1 = dorow(E10, E11, E12, E13, W10, W11, W12, W13, v1);

  // ---- block reductions: lloc, vsum[4], acc[32], esum[32] ----
  #pragma unroll
  for (int off = 32; off; off >>= 1) lloc += __shfl_xor(lloc, off);
  float v4s[4] = {vs0, vs1, vs2, vs3};
  #pragma unroll
  for (int f = 0; f < 4; f++) {
    float x = v4s[f];
    #pragma unroll
    for (int off = 32; off; off >>= 1) x += __shfl_xor(x, off);
    if (lane == 0) sred[wv][65 + f] = x;
  }
  if (lane == 0) sred[wv][64] = lloc;
  #pragma unroll
  for (int k = 0; k < D; k++) {
    float a = acc[k], e = esum[k];
    #pragma unroll
    for (int off = 32; off; off >>= 1) { a += __shfl_xor(a, off); e += __shfl_xor(e, off); }
    if (lane == 0) { sred[wv][k] = a; sred[wv][D + k] = e; }
  }
  __syncthreads();
  if (tid == 0) sL[0] = sred[0][64] + sred[1][64] + sred[2][64] + sred[3][64];
  __syncthreads();
  const float invL = 1.f / sL[0];

  out_attn[(size_t)b * SV + j0] = e0 * invL;
  if (has1) out_attn[(size_t)b * SV + j1] = e1 * invL;

  if (tid < D) {
    const float aS = sred[0][tid] + sred[1][tid] + sred[2][tid] + sred[3][tid];
    const float eS = sred[0][D + tid] + sred[1][D + tid] + sred[2][D + tid] + sred[3][D + tid];
    float vp = 0.f;
    #pragma unroll
    for (int f = 0; f < 4; f++) {
      const float vf = sred[0][65 + f] + sred[1][65 + f] + sred[2][65 + f] + sred[3][65 + f];
      vp += vf * W_num[f * D + tid];
    }
    const float q  = sQS[tid][0] - wsc[128 + tid];
    const float eo = aS * invL - q;                     // acc held e*(q+val): undo q
    out_emb[(size_t)b * D + tid] = eo;
    sctx[tid] = eo + (eS + vp + (float)SV * b_num[tid] + smixq[tid]) * (1.f / (float)S);
  }
  __syncthreads();

  // ---- predictor head on wave 0; weights direct from global (L2-hot) ----
  if (tid < H) {
    float hv = bp[tid];
    #pragma unroll
    for (int d = 0; d < D; d++) hv += sctx[d] * Wp[d * H + tid];
    hv = fmaxf(hv, 0.f);
    float mu = hv;
    #pragma unroll
    for (int off = 32; off; off >>= 1) mu += __shfl_xor(mu, off);
    mu *= (1.f / 64.f);
    const float dv = hv - mu;
    float vvv = dv * dv;
    #pragma unroll
    for (int off = 32; off; off >>= 1) vvv += __shfl_xor(vvv, off);
    vvv *= (1.f / 64.f);
    const float hn = dv * rsqrtf(vvv + 1e-3f) * ln_g[tid] + ln_b[tid];
    out_h[(size_t)b * H + tid] = hn;
    float s0 = hn * Ws[2 * tid], s1 = hn * Ws[2 * tid + 1];
    #pragma unroll
    for (int off = 32; off; off >>= 1) { s0 += __shfl_xor(s0, off); s1 += __shfl_xor(s1, off); }
    if (tid == 0) {
      const float mx = fmaxf(s0, s1);
      const float a0 = __expf(s0 - mx), a1 = __expf(s1 - mx);
      const float inv = 1.f / (a0 + a1);
      out_score[(size_t)b * 2]     = a0 * inv;
      out_score[(size_t)b * 2 + 1] = a1 * inv;
    }
  }
}

// ================= fallback (no-workspace) kernel: per-row GEMV =================
__global__ __launch_bounds__(BDIM) void attn_fused_gemv(
    const float* __restrict__ values, const int* __restrict__ names,
    const float* __restrict__ emb,
    const float* __restrict__ W_num, const float* __restrict__ b_num,
    const float* __restrict__ Wq,    const float* __restrict__ bq,
    const float* __restrict__ Wv,    const float* __restrict__ bv,
    const float* __restrict__ attn_scale,
    const float* __restrict__ Wp,    const float* __restrict__ bp,
    const float* __restrict__ ln_g,  const float* __restrict__ ln_b,
    const float* __restrict__ Ws,
    float* __restrict__ out_score, float* __restrict__ out_emb,
    float* __restrict__ out_attn,  float* __restrict__ out_h)
{
  __shared__ float sWnum[F * D];
  __shared__ float sbnum[D];
  __shared__ float sWq[D * D];
  __shared__ float sWv[D * D];
  __shared__ float sbv[D];
  __shared__ float sscale[D];
  __shared__ float sq[D];
  __shared__ float smixq[D];
  __shared__ float sred[4][2 * D];
  __shared__ float sredS[4];
  __shared__ float sML[2];
  __shared__ float sctx[D];
  __shared__ float sWp[D * H];

  const int b = blockIdx.x, tid = threadIdx.x, lane = tid & 63, wv = tid >> 6;

  for (int i = tid; i < F * D; i += BDIM) sWnum[i] = W_num[i];
  if (tid < D) { sbnum[tid] = b_num[tid]; sbv[tid] = bv[tid]; sscale[tid] = attn_scale[tid]; }
  for (int i = tid; i < D * D; i += BDIM) { sWq[i] = Wq[i]; sWv[i] = Wv[i]; }
  for (int i = tid; i < D * H; i += BDIM) sWp[i] = Wp[i];
  __syncthreads();

  if (tid < D) {
    const int    name = names[b * S + (S - 1)];
    const float* vr   = values + (size_t)(b * S + (S - 1)) * F;
    smixq[tid] = emb[(size_t)name * D + tid] + sbnum[tid]
               + vr[0] * sWnum[tid] + vr[1] * sWnum[D + tid]
               + vr[2] * sWnum[2 * D + tid] + vr[3] * sWnum[3 * D + tid];
  }
  __syncthreads();
  if (tid < D) {
    float a = bq[tid];
    #pragma unroll
    for (int k = 0; k < D; k++) a += smixq[k] * sWq[k * D + tid];
    sq[tid] = a;
  }
  __syncthreads();

  float msum[D], acc[D];
  #pragma unroll
  for (int k = 0; k < D; k++) { msum[k] = 0.f; acc[k] = 0.f; }
  float mloc = -INFINITY, lloc = 0.f;
  float sc0 = 0.f, sc1 = 0.f;
  const bool has2 = (tid < SV - BDIM);

  auto row = [&](int j, float& sout) {
    const int    name = names[b * S + j];
    const float4 v4   = *reinterpret_cast<const float4*>(values + (size_t)(b * S + j) * F);
    const float4* e4p = reinterpret_cast<const float4*>(emb + (size_t)name * D);
    float mix[D];
    #pragma unroll
    for (int c = 0; c < 8; c++) {
      const float4 e = e4p[c];
      mix[4 * c] = e.x; mix[4 * c + 1] = e.y; mix[4 * c + 2] = e.z; mix[4 * c + 3] = e.w;
    }
    #pragma unroll
    for (int k = 0; k < D; k++) {
      mix[k] += sbnum[k] + v4.x * sWnum[k] + v4.y * sWnum[D + k]
              + v4.z * sWnum[2 * D + k] + v4.w * sWnum[3 * D + k];
      msum[k] += mix[k];
    }
    float val[D];
    #pragma unroll
    for (int k = 0; k < D; k++) val[k] = sbv[k];
    for (int m = 0; m < D; m++) {
      const float mv = mix[m];
      #pragma unroll
      for (int k = 0; k < D; k++) val[k] += mv * sWv[m * D + k];
    }
    float s = 0.f;
    #pragma unroll
    for (int k = 0; k < D; k++) s += sscale[k] * fast_tanh(sq[k] + val[k]);
    sout = s;
    float w;
    if (s > mloc) {
      const float sf = __expf(mloc - s);
      lloc *= sf;
      #pragma unroll
      for (int k = 0; k < D; k++) acc[k] *= sf;
      mloc = s; w = 1.f;
    } else {
      w = __expf(s - mloc);
    }
    lloc += w;
    #pragma unroll
    for (int k = 0; k < D; k++) acc[k] += w * val[k];
  };

  row(tid, sc0);
  if (has2) row(tid + BDIM, sc1);

  float mw = mloc;
  #pragma unroll
  for (int off = 32; off; off >>= 1) mw = fmaxf(mw, __shfl_xor(mw, off));
  if (lane == 0) sredS[wv] = mw;
  __syncthreads();
  if (tid == 0) sML[0] = fmaxf(fmaxf(sredS[0], sredS[1]), fmaxf(sredS[2], sredS[3]));
  __syncthreads();
  const float M = sML[0];
  {
    const float adj = __expf(mloc - M);
    lloc *= adj;
    #pragma unroll
    for (int k = 0; k < D; k++) acc[k] *= adj;
  }
  float lw = lloc;
  #pragma unroll
  for (int off = 32; off; off >>= 1) lw += __shfl_xor(lw, off);
  if (lane == 0) sredS[wv] = lw;
  #pragma unroll
  for (int k = 0; k < D; k++) {
    float a = acc[k], mm = msum[k];
    #pragma unroll
    for (int off = 32; off; off >>= 1) { a += __shfl_xor(a, off); mm += __shfl_xor(mm, off); }
    if (lane == 0) { sred[wv][k] = a; sred[wv][D + k] = mm; }
  }
  __syncthreads();
  if (tid == 0) sML[1] = sredS[0] + sredS[1] + sredS[2] + sredS[3];
  __syncthreads();
  const float L = sML[1], invL = 1.f / L;

  out_attn[(size_t)b * SV + tid] = __expf(sc0 - M) * invL;
  if (has2) out_attn[(size_t)b * SV + tid + BDIM] = __expf(sc1 - M) * invL;

  if (tid < D) {
    const float a  = sred[0][tid] + sred[1][tid] + sred[2][tid] + sred[3][tid];
    const float mm = sred[0][D + tid] + sred[1][D + tid] + sred[2][D + tid] + sred[3][D + tid];
    const float eo = a * invL;
    out_emb[(size_t)b * D + tid] = eo;
    sctx[tid] = eo + (mm + smixq[tid]) * (1.f / (float)S);
  }
  __syncthreads();

  if (tid < H) {
    float hv = bp[tid];
    #pragma unroll
    for (int d = 0; d < D; d++) hv += sctx[d] * sWp[d * H + tid];
    hv = fmaxf(hv, 0.f);
    float mu = hv;
    #pragma unroll
    for (int off = 32; off; off >>= 1) mu += __shfl_xor(mu, off);
    mu *= (1.f / 64.f);
    const float dv = hv - mu;
    float vv = dv * dv;
    #pragma unroll
    for (int off = 32; off; off >>= 1) vv += __shfl_xor(vv, off);
    vv *= (1.f / 64.f);
    const float hn = dv * rsqrtf(vv + 1e-3f) * ln_g[tid] + ln_b[tid];
    out_h[(size_t)b * H + tid] = hn;
    float s0 = hn * Ws[2 * tid], s1 = hn * Ws[2 * tid + 1];
    #pragma unroll
    for (int off = 32; off; off >>= 1) { s0 += __shfl_xor(s0, off); s1 += __shfl_xor(s1, off); }
    if (tid == 0) {
      const float mx = fmaxf(s0, s1);
      const float a0 = __expf(s0 - mx), a1 = __expf(s1 - mx);
      const float inv = 1.f / (a0 + a1);
      out_score[(size_t)b * 2]     = a0 * inv;
      out_score[(size_t)b * 2 + 1] = a1 * inv;
    }
  }
}

extern "C" void kernel_launch(void* const* d_in, const int* in_sizes, int n_in,
                              void* d_out, int out_size, void* d_ws, size_t ws_size,
                              hipStream_t stream) {
  const float* values = (const float*)d_in[0];
  const int*   names  = (const int*)d_in[1];
  const float* emb    = (const float*)d_in[2];
  const float* W_num  = (const float*)d_in[3];
  const float* b_num  = (const float*)d_in[4];
  const float* Wq     = (const float*)d_in[5];
  const float* bq     = (const float*)d_in[6];
  const float* Wv     = (const float*)d_in[7];
  const float* bv     = (const float*)d_in[8];
  const float* scal   = (const float*)d_in[9];
  const float* Wp     = (const float*)d_in[10];
  const float* bp     = (const float*)d_in[11];
  const float* ln_g   = (const float*)d_in[12];
  const float* ln_b   = (const float*)d_in[13];
  const float* Ws     = (const float*)d_in[14];

  float* out      = (float*)d_out;
  float* o_score  = out;
  float* o_emb    = o_score + (size_t)Bsz * 2;
  float* o_attn   = o_emb   + (size_t)Bsz * D;
  float* o_h      = o_attn  + (size_t)Bsz * SV;

  const size_t need = TAB_BYTES + 256 * sizeof(float);
  if (ws_size >= need) {
    __hip_bfloat16* T = (__hip_bfloat16*)d_ws;
    float* wsc = (float*)((char*)d_ws + TAB_BYTES);
    hipLaunchKernelGGL(build_tab, dim3((VOCAB + 7) / 8 + 1), dim3(BDIM), 0, stream,
                       emb, Wv, W_num, b_num, bv, T, wsc);
    hipLaunchKernelGGL(attn_main, dim3(Bsz), dim3(BDIM), 0, stream,
                       values, names, T, wsc, emb, W_num, b_num, Wq, bq, scal,
                       Wp, bp, ln_g, ln_b, Ws, o_score, o_emb, o_attn, o_h);
  } else {
    hipLaunchKernelGGL(attn_fused_gemv, dim3(Bsz), dim3(BDIM), 0, stream,
                       values, names, emb, W_num, b_num, Wq, bq, Wv, bv, scal,
                       Wp, bp, ln_g, ln_b, Ws, o_score, o_emb, o_attn, o_h);
  }
}

// Round 7
// 151.448 us; speedup vs baseline: 1.1700x; 1.1700x over previous
//
#include <hip/hip_runtime.h>
#include <hip/hip_bf16.h>
#include <math.h>

constexpr int Bsz   = 1024;
constexpr int S     = 512;
constexpr int SV    = 511;   // attention rows (all but last)
constexpr int D     = 32;
constexpr int F     = 4;
constexpr int H     = 64;
constexpr int BDIM  = 256;
constexpr int VOCAB = 100001;
constexpr size_t TAB_BYTES = (size_t)VOCAB * 64 * 2;   // bf16 table

__device__ __forceinline__ float fast_tanh(float x) {
  // tanh(x) = 1 - 2/(e^{2x}+1); exp overflow -> inf -> rcp -> 0 -> 1 (correct limit)
  const float ex = __expf(2.f * x);
  return 1.f - 2.f * __builtin_amdgcn_rcpf(ex + 1.f);
}

__device__ __forceinline__ void unpack8(uint4 u, float* f) {
  // 8 bf16 (little-endian packed) -> 8 f32 via bit shifts (no cvt ops)
  f[0] = __uint_as_float(u.x << 16); f[1] = __uint_as_float(u.x & 0xffff0000u);
  f[2] = __uint_as_float(u.y << 16); f[3] = __uint_as_float(u.y & 0xffff0000u);
  f[4] = __uint_as_float(u.z << 16); f[5] = __uint_as_float(u.z & 0xffff0000u);
  f[6] = __uint_as_float(u.w << 16); f[7] = __uint_as_float(u.w & 0xffff0000u);
}

// ---- build: T16[VOCAB][64] = bf16[ emb_row | emb_row @ Wv ];  last block: W2T/bias2 ----
__global__ __launch_bounds__(BDIM) void build_tab(
    const float* __restrict__ emb, const float* __restrict__ Wv,
    const float* __restrict__ W_num, const float* __restrict__ b_num,
    const float* __restrict__ bv,
    __hip_bfloat16* __restrict__ T, float* __restrict__ wsc)
{
  __shared__ float sWv[D * D];
  for (int i = threadIdx.x; i < D * D; i += BDIM) sWv[i] = Wv[i];
  __syncthreads();

  if (blockIdx.x == gridDim.x - 1) {
    const int tid = threadIdx.x;
    if (tid < F * D) {                     // W2[f][k] stored transposed: wsc[k*4+f]
      const int f = tid >> 5, k = tid & 31;
      float a = 0.f;
      #pragma unroll
      for (int m = 0; m < D; m++) a += W_num[f * D + m] * sWv[m * D + k];
      wsc[k * 4 + f] = a;
    } else if (tid < F * D + D) {          // bias2[k] = bv + b_num@Wv at wsc[128+k]
      const int k = tid - F * D;
      float a = bv[k];
      #pragma unroll
      for (int m = 0; m < D; m++) a += b_num[m] * sWv[m * D + k];
      wsc[F * D + k] = a;
    }
    return;
  }

  const int lr = threadIdx.x >> 5, k = threadIdx.x & 31;
  const int row = blockIdx.x * 8 + lr;
  if (row < VOCAB) {
    const float4* e4 = reinterpret_cast<const float4*>(emb + (size_t)row * D);
    float a = 0.f;
    #pragma unroll
    for (int c = 0; c < 8; c++) {
      const float4 v = e4[c];
      a += v.x * sWv[(4 * c + 0) * D + k] + v.y * sWv[(4 * c + 1) * D + k]
         + v.z * sWv[(4 * c + 2) * D + k] + v.w * sWv[(4 * c + 3) * D + k];
    }
    T[(size_t)row * 64 + k]      = __float2bfloat16(emb[(size_t)row * D + k]);
    T[(size_t)row * 64 + 32 + k] = __float2bfloat16(a);
  }
}

// ================= main fused kernel: lane-split over D, 8 passes =================
__global__ __launch_bounds__(BDIM, 4) void attn_main(
    const float* __restrict__ values, const int* __restrict__ names,
    const __hip_bfloat16* __restrict__ T, const float* __restrict__ wsc,
    const float* __restrict__ emb,
    const float* __restrict__ W_num, const float* __restrict__ b_num,
    const float* __restrict__ Wq,    const float* __restrict__ bq,
    const float* __restrict__ attn_scale,
    const float* __restrict__ Wp,    const float* __restrict__ bp,
    const float* __restrict__ ln_g,  const float* __restrict__ ln_b,
    const float* __restrict__ Ws,
    float* __restrict__ out_score, float* __restrict__ out_emb,
    float* __restrict__ out_attn,  float* __restrict__ out_h)
{
  __shared__ float sW2T[D][4];   // W2 transposed: [k][f]
  __shared__ float sQS[D][2];    // {q+bias2, scale}
  __shared__ float smixq[D];
  __shared__ float sred[4][69];  // per wave: acc[32], esum[32], lloc, vsum[4]
  __shared__ float sctx[D];
  __shared__ float sL[1];
  __shared__ float sE[512];      // per-row e values

  const int b = blockIdx.x, tid = threadIdx.x, lane = tid & 63, wv = tid >> 6;
  const int rg = lane >> 2, kl = lane & 3;       // 16 row-groups x 4 k-lanes
  const int rbase = wv * 16 + rg;                // row offset within a pass

  if (tid < 128) sW2T[tid >> 2][tid & 3] = wsc[tid];
  if (tid < D) {
    const int    nq = names[b * S + (S - 1)];
    const float* vr = values + (size_t)(b * S + (S - 1)) * F;
    smixq[tid] = emb[(size_t)nq * D + tid] + b_num[tid]
               + vr[0] * W_num[tid] + vr[1] * W_num[D + tid]
               + vr[2] * W_num[2 * D + tid] + vr[3] * W_num[3 * D + tid];
  }
  __syncthreads();
  if (tid < D) {
    float a = bq[tid];
    #pragma unroll
    for (int m = 0; m < D; m++) a += smixq[m] * Wq[m * D + tid];
    sQS[tid][0] = a + wsc[128 + tid];   // q + bias2
    sQS[tid][1] = attn_scale[tid];
  }
  __syncthreads();

  // ---- cache k-slice invariants in registers (k = kl*8 + i) ----
  float qb[8], scl[8], w2a[8], w2b[8], w2c[8], w2d[8];
  #pragma unroll
  for (int i = 0; i < 8; i++) {
    const int k = kl * 8 + i;
    qb[i]  = sQS[k][0]; scl[i] = sQS[k][1];
    w2a[i] = sW2T[k][0]; w2b[i] = sW2T[k][1];
    w2c[i] = sW2T[k][2]; w2d[i] = sW2T[k][3];
  }

  // ---- all 8 pass names upfront (j = p*64 + rbase; j=511 is a safe load) ----
  int nm[8];
  #pragma unroll
  for (int p = 0; p < 8; p++) nm[p] = names[b * S + p * 64 + rbase];

  float esum[8], acc[8];
  #pragma unroll
  for (int i = 0; i < 8; i++) { esum[i] = 0.f; acc[i] = 0.f; }
  float lloc = 0.f, vs0 = 0.f, vs1 = 0.f, vs2 = 0.f, vs3 = 0.f;

  const char* Tb = (const char*)T;
  uint4 Ec, Wc, En, Wn; float4 vc, vn;
  {
    const char* p0 = Tb + (size_t)nm[0] * 128 + kl * 16;
    Ec = *(const uint4*)p0; Wc = *(const uint4*)(p0 + 64);
    vc = *reinterpret_cast<const float4*>(values + (size_t)(b * S + rbase) * F);
    const char* p1 = Tb + (size_t)nm[1] * 128 + kl * 16;
    En = *(const uint4*)p1; Wn = *(const uint4*)(p1 + 64);
    vn = *reinterpret_cast<const float4*>(values + (size_t)(b * S + 64 + rbase) * F);
  }

  #pragma unroll
  for (int p = 0; p < 8; p++) {
    float em[8], w[8], t[8];
    unpack8(Ec, em); unpack8(Wc, w);
    float s = 0.f;
    #pragma unroll
    for (int i = 0; i < 8; i++) {
      t[i] = w[i] + qb[i] + vc.x * w2a[i] + vc.y * w2b[i]
           + vc.z * w2c[i] + vc.w * w2d[i];          // t = q + val (k-slice)
      s += scl[i] * fast_tanh(t[i]);
    }
    const float4 vcur = vc;
    // rotate buffers, prefetch pass p+2 (overlaps exp + next pass compute)
    Ec = En; Wc = Wn; vc = vn;
    if (p + 2 < 8) {
      const char* pn = Tb + (size_t)nm[p + 2] * 128 + kl * 16;
      En = *(const uint4*)pn; Wn = *(const uint4*)(pn + 64);
      vn = *reinterpret_cast<const float4*>(values + (size_t)(b * S + (p + 2) * 64 + rbase) * F);
    }
    s += __shfl_xor(s, 1); s += __shfl_xor(s, 2);    // full 32-k score
    const bool  valid = (p * 64 + rbase) < SV;       // only j==511 invalid
    const float e = valid ? __expf(s) : 0.f;         // |s| <= 32, no overflow
    lloc += e;
    if (kl == 0) sE[p * 64 + rbase] = e;
    if (valid) {
      vs0 += vcur.x; vs1 += vcur.y; vs2 += vcur.z; vs3 += vcur.w;
      #pragma unroll
      for (int i = 0; i < 8; i++) esum[i] += em[i];
    }
    #pragma unroll
    for (int i = 0; i < 8; i++) acc[i] = fmaf(e, t[i], acc[i]);
  }

  // ---- reduce across 16 row-groups (xor 4..32); kl lanes hold distinct k-slices ----
  #pragma unroll
  for (int off = 4; off < 64; off <<= 1) {
    lloc += __shfl_xor(lloc, off);
    vs0 += __shfl_xor(vs0, off); vs1 += __shfl_xor(vs1, off);
    vs2 += __shfl_xor(vs2, off); vs3 += __shfl_xor(vs3, off);
    #pragma unroll
    for (int i = 0; i < 8; i++) {
      acc[i]  += __shfl_xor(acc[i], off);
      esum[i] += __shfl_xor(esum[i], off);
    }
  }
  if (lane < 4) {
    #pragma unroll
    for (int i = 0; i < 8; i++) {
      sred[wv][lane * 8 + i]      = acc[i];
      sred[wv][32 + lane * 8 + i] = esum[i];
    }
  }
  if (lane == 0) {
    sred[wv][64] = lloc;
    sred[wv][65] = vs0; sred[wv][66] = vs1; sred[wv][67] = vs2; sred[wv][68] = vs3;
  }
  __syncthreads();
  if (tid == 0) sL[0] = sred[0][64] + sred[1][64] + sred[2][64] + sred[3][64];
  __syncthreads();
  const float invL = 1.f / sL[0];

  // ---- attention weights out (coalesced from LDS) ----
  for (int idx = tid; idx < SV; idx += BDIM)
    out_attn[(size_t)b * SV + idx] = sE[idx] * invL;

  // ---- emb_out + context ----
  if (tid < D) {
    const float aS = sred[0][tid] + sred[1][tid] + sred[2][tid] + sred[3][tid];
    const float eS = sred[0][D + tid] + sred[1][D + tid] + sred[2][D + tid] + sred[3][D + tid];
    float vp = 0.f;
    #pragma unroll
    for (int f = 0; f < 4; f++) {
      const float vf = sred[0][65 + f] + sred[1][65 + f] + sred[2][65 + f] + sred[3][65 + f];
      vp += vf * W_num[f * D + tid];
    }
    const float q  = sQS[tid][0] - wsc[128 + tid];
    const float eo = aS * invL - q;                     // acc held e*(q+val): undo q
    out_emb[(size_t)b * D + tid] = eo;
    sctx[tid] = eo + (eS + vp + (float)SV * b_num[tid] + smixq[tid]) * (1.f / (float)S);
  }
  __syncthreads();

  // ---- predictor head on wave 0 ----
  if (tid < H) {
    float hv = bp[tid];
    #pragma unroll
    for (int d = 0; d < D; d++) hv += sctx[d] * Wp[d * H + tid];
    hv = fmaxf(hv, 0.f);
    float mu = hv;
    #pragma unroll
    for (int off = 32; off; off >>= 1) mu += __shfl_xor(mu, off);
    mu *= (1.f / 64.f);
    const float dv = hv - mu;
    float vvv = dv * dv;
    #pragma unroll
    for (int off = 32; off; off >>= 1) vvv += __shfl_xor(vvv, off);
    vvv *= (1.f / 64.f);
    const float hn = dv * rsqrtf(vvv + 1e-3f) * ln_g[tid] + ln_b[tid];
    out_h[(size_t)b * H + tid] = hn;
    float s0 = hn * Ws[2 * tid], s1 = hn * Ws[2 * tid + 1];
    #pragma unroll
    for (int off = 32; off; off >>= 1) { s0 += __shfl_xor(s0, off); s1 += __shfl_xor(s1, off); }
    if (tid == 0) {
      const float mx = fmaxf(s0, s1);
      const float a0 = __expf(s0 - mx), a1 = __expf(s1 - mx);
      const float inv = 1.f / (a0 + a1);
      out_score[(size_t)b * 2]     = a0 * inv;
      out_score[(size_t)b * 2 + 1] = a1 * inv;
    }
  }
}

// ================= fallback (no-workspace) kernel: per-row GEMV =================
__global__ __launch_bounds__(BDIM) void attn_fused_gemv(
    const float* __restrict__ values, const int* __restrict__ names,
    const float* __restrict__ emb,
    const float* __restrict__ W_num, const float* __restrict__ b_num,
    const float* __restrict__ Wq,    const float* __restrict__ bq,
    const float* __restrict__ Wv,    const float* __restrict__ bv,
    const float* __restrict__ attn_scale,
    const float* __restrict__ Wp,    const float* __restrict__ bp,
    const float* __restrict__ ln_g,  const float* __restrict__ ln_b,
    const float* __restrict__ Ws,
    float* __restrict__ out_score, float* __restrict__ out_emb,
    float* __restrict__ out_attn,  float* __restrict__ out_h)
{
  __shared__ float sWnum[F * D];
  __shared__ float sbnum[D];
  __shared__ float sWq[D * D];
  __shared__ float sWv[D * D];
  __shared__ float sbv[D];
  __shared__ float sscale[D];
  __shared__ float sq[D];
  __shared__ float smixq[D];
  __shared__ float sred[4][2 * D];
  __shared__ float sredS[4];
  __shared__ float sML[2];
  __shared__ float sctx[D];
  __shared__ float sWp[D * H];

  const int b = blockIdx.x, tid = threadIdx.x, lane = tid & 63, wv = tid >> 6;

  for (int i = tid; i < F * D; i += BDIM) sWnum[i] = W_num[i];
  if (tid < D) { sbnum[tid] = b_num[tid]; sbv[tid] = bv[tid]; sscale[tid] = attn_scale[tid]; }
  for (int i = tid; i < D * D; i += BDIM) { sWq[i] = Wq[i]; sWv[i] = Wv[i]; }
  for (int i = tid; i < D * H; i += BDIM) sWp[i] = Wp[i];
  __syncthreads();

  if (tid < D) {
    const int    name = names[b * S + (S - 1)];
    const float* vr   = values + (size_t)(b * S + (S - 1)) * F;
    smixq[tid] = emb[(size_t)name * D + tid] + sbnum[tid]
               + vr[0] * sWnum[tid] + vr[1] * sWnum[D + tid]
               + vr[2] * sWnum[2 * D + tid] + vr[3] * sWnum[3 * D + tid];
  }
  __syncthreads();
  if (tid < D) {
    float a = bq[tid];
    #pragma unroll
    for (int k = 0; k < D; k++) a += smixq[k] * sWq[k * D + tid];
    sq[tid] = a;
  }
  __syncthreads();

  float msum[D], acc[D];
  #pragma unroll
  for (int k = 0; k < D; k++) { msum[k] = 0.f; acc[k] = 0.f; }
  float mloc = -INFINITY, lloc = 0.f;
  float sc0 = 0.f, sc1 = 0.f;
  const bool has2 = (tid < SV - BDIM);

  auto row = [&](int j, float& sout) {
    const int    name = names[b * S + j];
    const float4 v4   = *reinterpret_cast<const float4*>(values + (size_t)(b * S + j) * F);
    const float4* e4p = reinterpret_cast<const float4*>(emb + (size_t)name * D);
    float mix[D];
    #pragma unroll
    for (int c = 0; c < 8; c++) {
      const float4 e = e4p[c];
      mix[4 * c] = e.x; mix[4 * c + 1] = e.y; mix[4 * c + 2] = e.z; mix[4 * c + 3] = e.w;
    }
    #pragma unroll
    for (int k = 0; k < D; k++) {
      mix[k] += sbnum[k] + v4.x * sWnum[k] + v4.y * sWnum[D + k]
              + v4.z * sWnum[2 * D + k] + v4.w * sWnum[3 * D + k];
      msum[k] += mix[k];
    }
    float val[D];
    #pragma unroll
    for (int k = 0; k < D; k++) val[k] = sbv[k];
    for (int m = 0; m < D; m++) {
      const float mv = mix[m];
      #pragma unroll
      for (int k = 0; k < D; k++) val[k] += mv * sWv[m * D + k];
    }
    float s = 0.f;
    #pragma unroll
    for (int k = 0; k < D; k++) s += sscale[k] * fast_tanh(sq[k] + val[k]);
    sout = s;
    float w;
    if (s > mloc) {
      const float sf = __expf(mloc - s);
      lloc *= sf;
      #pragma unroll
      for (int k = 0; k < D; k++) acc[k] *= sf;
      mloc = s; w = 1.f;
    } else {
      w = __expf(s - mloc);
    }
    lloc += w;
    #pragma unroll
    for (int k = 0; k < D; k++) acc[k] += w * val[k];
  };

  row(tid, sc0);
  if (has2) row(tid + BDIM, sc1);

  float mw = mloc;
  #pragma unroll
  for (int off = 32; off; off >>= 1) mw = fmaxf(mw, __shfl_xor(mw, off));
  if (lane == 0) sredS[wv] = mw;
  __syncthreads();
  if (tid == 0) sML[0] = fmaxf(fmaxf(sredS[0], sredS[1]), fmaxf(sredS[2], sredS[3]));
  __syncthreads();
  const float M = sML[0];
  {
    const float adj = __expf(mloc - M);
    lloc *= adj;
    #pragma unroll
    for (int k = 0; k < D; k++) acc[k] *= adj;
  }
  float lw = lloc;
  #pragma unroll
  for (int off = 32; off; off >>= 1) lw += __shfl_xor(lw, off);
  if (lane == 0) sredS[wv] = lw;
  #pragma unroll
  for (int k = 0; k < D; k++) {
    float a = acc[k], mm = msum[k];
    #pragma unroll
    for (int off = 32; off; off >>= 1) { a += __shfl_xor(a, off); mm += __shfl_xor(mm, off); }
    if (lane == 0) { sred[wv][k] = a; sred[wv][D + k] = mm; }
  }
  __syncthreads();
  if (tid == 0) sML[1] = sredS[0] + sredS[1] + sredS[2] + sredS[3];
  __syncthreads();
  const float L = sML[1], invL = 1.f / L;

  out_attn[(size_t)b * SV + tid] = __expf(sc0 - M) * invL;
  if (has2) out_attn[(size_t)b * SV + tid + BDIM] = __expf(sc1 - M) * invL;

  if (tid < D) {
    const float a  = sred[0][tid] + sred[1][tid] + sred[2][tid] + sred[3][tid];
    const float mm = sred[0][D + tid] + sred[1][D + tid] + sred[2][D + tid] + sred[3][D + tid];
    const float eo = a * invL;
    out_emb[(size_t)b * D + tid] = eo;
    sctx[tid] = eo + (mm + smixq[tid]) * (1.f / (float)S);
  }
  __syncthreads();

  if (tid < H) {
    float hv = bp[tid];
    #pragma unroll
    for (int d = 0; d < D; d++) hv += sctx[d] * sWp[d * H + tid];
    hv = fmaxf(hv, 0.f);
    float mu = hv;
    #pragma unroll
    for (int off = 32; off; off >>= 1) mu += __shfl_xor(mu, off);
    mu *= (1.f / 64.f);
    const float dv = hv - mu;
    float vv = dv * dv;
    #pragma unroll
    for (int off = 32; off; off >>= 1) vv += __shfl_xor(vv, off);
    vv *= (1.f / 64.f);
    const float hn = dv * rsqrtf(vv + 1e-3f) * ln_g[tid] + ln_b[tid];
    out_h[(size_t)b * H + tid] = hn;
    float s0 = hn * Ws[2 * tid], s1 = hn * Ws[2 * tid + 1];
    #pragma unroll
    for (int off = 32; off; off >>= 1) { s0 += __shfl_xor(s0, off); s1 += __shfl_xor(s1, off); }
    if (tid == 0) {
      const float mx = fmaxf(s0, s1);
      const float a0 = __expf(s0 - mx), a1 = __expf(s1 - mx);
      const float inv = 1.f / (a0 + a1);
      out_score[(size_t)b * 2]     = a0 * inv;
      out_score[(size_t)b * 2 + 1] = a1 * inv;
    }
  }
}

extern "C" void kernel_launch(void* const* d_in, const int* in_sizes, int n_in,
                              void* d_out, int out_size, void* d_ws, size_t ws_size,
                              hipStream_t stream) {
  const float* values = (const float*)d_in[0];
  const int*   names  = (const int*)d_in[1];
  const float* emb    = (const float*)d_in[2];
  const float* W_num  = (const float*)d_in[3];
  const float* b_num  = (const float*)d_in[4];
  const float* Wq     = (const float*)d_in[5];
  const float* bq     = (const float*)d_in[6];
  const float* Wv     = (const float*)d_in[7];
  const float* bv     = (const float*)d_in[8];
  const float* scal   = (const float*)d_in[9];
  const float* Wp     = (const float*)d_in[10];
  const float* bp     = (const float*)d_in[11];
  const float* ln_g   = (const float*)d_in[12];
  const float* ln_b   = (const float*)d_in[13];
  const float* Ws     = (const float*)d_in[14];

  float* out      = (float*)d_out;
  float* o_score  = out;
  float* o_emb    = o_score + (size_t)Bsz * 2;
  float* o_attn   = o_emb   + (size_t)Bsz * D;
  float* o_h      = o_attn  + (size_t)Bsz * SV;

  const size_t need = TAB_BYTES + 256 * sizeof(float);
  if (ws_size >= need) {
    __hip_bfloat16* T = (__hip_bfloat16*)d_ws;
    float* wsc = (float*)((char*)d_ws + TAB_BYTES);
    hipLaunchKernelGGL(build_tab, dim3((VOCAB + 7) / 8 + 1), dim3(BDIM), 0, stream,
                       emb, Wv, W_num, b_num, bv, T, wsc);
    hipLaunchKernelGGL(attn_main, dim3(Bsz), dim3(BDIM), 0, stream,
                       values, names, T, wsc, emb, W_num, b_num, Wq, bq, scal,
                       Wp, bp, ln_g, ln_b, Ws, o_score, o_emb, o_attn, o_h);
  } else {
    hipLaunchKernelGGL(attn_fused_gemv, dim3(Bsz), dim3(BDIM), 0, stream,
                       values, names, emb, W_num, b_num, Wq, bq, Wv, bv, scal,
                       Wp, bp, ln_g, ln_b, Ws, o_score, o_emb, o_attn, o_h);
  }
}

// Round 8
// 132.611 us; speedup vs baseline: 1.3362x; 1.1420x over previous
//
#include <hip/hip_runtime.h>
#include <hip/hip_bf16.h>
#include <math.h>

constexpr int Bsz   = 1024;
constexpr int S     = 512;
constexpr int SV    = 511;   // attention rows (all but last)
constexpr int D     = 32;
constexpr int F     = 4;
constexpr int H     = 64;
constexpr int BDIM  = 256;
constexpr int VOCAB = 100001;
constexpr size_t TAB_BYTES = (size_t)VOCAB * 64 * 2;   // bf16 table

__device__ __forceinline__ float fast_tanh(float x) {
  // tanh(x) = 1 - 2/(e^{2x}+1); exp overflow -> inf -> rcp -> 0 -> 1 (correct limit)
  const float ex = __expf(2.f * x);
  return 1.f - 2.f * __builtin_amdgcn_rcpf(ex + 1.f);
}

__device__ __forceinline__ void unpack4(uint2 u, float* f) {
  f[0] = __uint_as_float(u.x << 16); f[1] = __uint_as_float(u.x & 0xffff0000u);
  f[2] = __uint_as_float(u.y << 16); f[3] = __uint_as_float(u.y & 0xffff0000u);
}

__device__ __forceinline__ void unpack8(uint4 u, float* f) {
  f[0] = __uint_as_float(u.x << 16); f[1] = __uint_as_float(u.x & 0xffff0000u);
  f[2] = __uint_as_float(u.y << 16); f[3] = __uint_as_float(u.y & 0xffff0000u);
  f[4] = __uint_as_float(u.z << 16); f[5] = __uint_as_float(u.z & 0xffff0000u);
  f[6] = __uint_as_float(u.w << 16); f[7] = __uint_as_float(u.w & 0xffff0000u);
}

// ---- build: T16[VOCAB][64] = bf16[ emb_row | emb_row @ Wv ];  last block: W2T/bias2 ----
__global__ __launch_bounds__(BDIM) void build_tab(
    const float* __restrict__ emb, const float* __restrict__ Wv,
    const float* __restrict__ W_num, const float* __restrict__ b_num,
    const float* __restrict__ bv,
    __hip_bfloat16* __restrict__ T, float* __restrict__ wsc)
{
  __shared__ float sWv[D * D];
  for (int i = threadIdx.x; i < D * D; i += BDIM) sWv[i] = Wv[i];
  __syncthreads();

  if (blockIdx.x == gridDim.x - 1) {
    const int tid = threadIdx.x;
    if (tid < F * D) {                     // W2[f][k] stored transposed: wsc[k*4+f]
      const int f = tid >> 5, k = tid & 31;
      float a = 0.f;
      #pragma unroll
      for (int m = 0; m < D; m++) a += W_num[f * D + m] * sWv[m * D + k];
      wsc[k * 4 + f] = a;
    } else if (tid < F * D + D) {          // bias2[k] = bv + b_num@Wv at wsc[128+k]
      const int k = tid - F * D;
      float a = bv[k];
      #pragma unroll
      for (int m = 0; m < D; m++) a += b_num[m] * sWv[m * D + k];
      wsc[F * D + k] = a;
    }
    return;
  }

  const int lr = threadIdx.x >> 5, k = threadIdx.x & 31;
  const int row = blockIdx.x * 8 + lr;
  if (row < VOCAB) {
    const float4* e4 = reinterpret_cast<const float4*>(emb + (size_t)row * D);
    float a = 0.f;
    #pragma unroll
    for (int c = 0; c < 8; c++) {
      const float4 v = e4[c];
      a += v.x * sWv[(4 * c + 0) * D + k] + v.y * sWv[(4 * c + 1) * D + k]
         + v.z * sWv[(4 * c + 2) * D + k] + v.w * sWv[(4 * c + 3) * D + k];
    }
    T[(size_t)row * 64 + k]      = __float2bfloat16(emb[(size_t)row * D + k]);
    T[(size_t)row * 64 + 32 + k] = __float2bfloat16(a);
  }
}

// ============ main fused kernel: 8 k-lanes x 4 elems, 16 passes, 4-deep pipeline ============
__global__ __launch_bounds__(BDIM) void attn_main(
    const float* __restrict__ values, const int* __restrict__ names,
    const __hip_bfloat16* __restrict__ T, const float* __restrict__ wsc,
    const float* __restrict__ emb,
    const float* __restrict__ W_num, const float* __restrict__ b_num,
    const float* __restrict__ Wq,    const float* __restrict__ bq,
    const float* __restrict__ attn_scale,
    const float* __restrict__ Wp,    const float* __restrict__ bp,
    const float* __restrict__ ln_g,  const float* __restrict__ ln_b,
    const float* __restrict__ Ws,
    float* __restrict__ out_score, float* __restrict__ out_emb,
    float* __restrict__ out_attn,  float* __restrict__ out_h)
{
  __shared__ float sW2T[D][4];   // W2 transposed: [k][f]
  __shared__ float sQS[D][2];    // {q+bias2, scale}
  __shared__ float smixq[D];
  __shared__ float sred[4][69];  // per wave: acc[32], esum[32], lloc, vsum[4]
  __shared__ float sctx[D];
  __shared__ float sL[1];
  __shared__ float sE[512];      // per-row e values
  __shared__ int   sNames[512];

  const int b = blockIdx.x, tid = threadIdx.x, lane = tid & 63, wv = tid >> 6;
  const int kl = lane & 7, rg = lane >> 3;       // 8 k-lanes x 8 row-groups
  const int rbase = wv * 8 + rg;                 // row offset within a pass (0..31)

  // ---- phase 1: stage names (coalesced int2), W2T, mixq ----
  reinterpret_cast<int2*>(sNames)[tid] = *reinterpret_cast<const int2*>(names + (size_t)b * S + tid * 2);
  if (tid < 128) sW2T[tid >> 2][tid & 3] = wsc[tid];
  if (tid < D) {
    const int    nq = names[(size_t)b * S + (S - 1)];
    const float* vr = values + (size_t)(b * S + (S - 1)) * F;
    smixq[tid] = emb[(size_t)nq * D + tid] + b_num[tid]
               + vr[0] * W_num[tid] + vr[1] * W_num[D + tid]
               + vr[2] * W_num[2 * D + tid] + vr[3] * W_num[3 * D + tid];
  }
  __syncthreads();
  if (tid < D) {
    float a = bq[tid];
    #pragma unroll
    for (int m = 0; m < D; m++) a += smixq[m] * Wq[m * D + tid];
    sQS[tid][0] = a + wsc[128 + tid];   // q + bias2
    sQS[tid][1] = attn_scale[tid];
  }
  __syncthreads();

  // ---- k-slice invariants in registers (k = kl*4 + i) ----
  float qb[4], scl[4], w2a[4], w2b[4], w2c[4], w2d[4];
  #pragma unroll
  for (int i = 0; i < 4; i++) {
    const int k = kl * 4 + i;
    qb[i]  = sQS[k][0]; scl[i] = sQS[k][1];
    w2a[i] = sW2T[k][0]; w2b[i] = sW2T[k][1];
    w2c[i] = sW2T[k][2]; w2d[i] = sW2T[k][3];
  }

  float esum[4] = {0.f, 0.f, 0.f, 0.f}, acc[4] = {0.f, 0.f, 0.f, 0.f};
  float lloc = 0.f, vs0 = 0.f, vs1 = 0.f, vs2 = 0.f, vs3 = 0.f;

  const char* Tb = (const char*)T;
  uint2 Eb[4], Wb[4]; float4 vb[4];

  #define ISSUE(P, ST) do {                                                    \
    const int   j_  = (P) * 32 + rbase;                                        \
    const int   nm_ = sNames[j_];                                              \
    const char* pr_ = Tb + (size_t)nm_ * 128 + kl * 8;                         \
    Eb[ST] = *(const uint2*)pr_;                                               \
    Wb[ST] = *(const uint2*)(pr_ + 64);                                        \
    vb[ST] = *reinterpret_cast<const float4*>(values + (size_t)(b * S + j_) * F); \
  } while (0)

  ISSUE(0, 0); ISSUE(1, 1); ISSUE(2, 2);

  #pragma unroll
  for (int p = 0; p < 16; p++) {
    const int st = p & 3;
    float em[4], w[4], t[4];
    unpack4(Eb[st], em); unpack4(Wb[st], w);
    const float4 vv = vb[st];
    if (p + 3 < 16) { const int sn = (p + 3) & 3; ISSUE(p + 3, sn); }
    float s = 0.f;
    #pragma unroll
    for (int i = 0; i < 4; i++) {
      t[i] = w[i] + qb[i] + vv.x * w2a[i] + vv.y * w2b[i]
           + vv.z * w2c[i] + vv.w * w2d[i];           // t = q + val (k-slice)
      s += scl[i] * fast_tanh(t[i]);
    }
    s += __shfl_xor(s, 1); s += __shfl_xor(s, 2); s += __shfl_xor(s, 4);
    const bool  valid = (p * 32 + rbase) < SV;        // only j==511 invalid
    const float e = valid ? __expf(s) : 0.f;          // |s| <= 32, no overflow
    lloc += e;
    if (kl == 0) sE[p * 32 + rbase] = e;
    if (valid) {
      vs0 += vv.x; vs1 += vv.y; vs2 += vv.z; vs3 += vv.w;
      #pragma unroll
      for (int i = 0; i < 4; i++) esum[i] += em[i];
    }
    #pragma unroll
    for (int i = 0; i < 4; i++) acc[i] = fmaf(e, t[i], acc[i]);
  }
  #undef ISSUE

  // ---- reduce across 8 row-groups (xor 8..32); kl lanes hold distinct k-slices ----
  #pragma unroll
  for (int off = 8; off < 64; off <<= 1) {
    lloc += __shfl_xor(lloc, off);
    vs0 += __shfl_xor(vs0, off); vs1 += __shfl_xor(vs1, off);
    vs2 += __shfl_xor(vs2, off); vs3 += __shfl_xor(vs3, off);
    #pragma unroll
    for (int i = 0; i < 4; i++) {
      acc[i]  += __shfl_xor(acc[i], off);
      esum[i] += __shfl_xor(esum[i], off);
    }
  }
  if (lane < 8) {
    #pragma unroll
    for (int i = 0; i < 4; i++) {
      sred[wv][lane * 4 + i]      = acc[i];
      sred[wv][32 + lane * 4 + i] = esum[i];
    }
  }
  if (lane == 0) {
    sred[wv][64] = lloc;
    sred[wv][65] = vs0; sred[wv][66] = vs1; sred[wv][67] = vs2; sred[wv][68] = vs3;
  }
  __syncthreads();
  if (tid == 0) sL[0] = sred[0][64] + sred[1][64] + sred[2][64] + sred[3][64];
  __syncthreads();
  const float invL = 1.f / sL[0];

  // ---- attention weights out (coalesced from LDS) ----
  for (int idx = tid; idx < SV; idx += BDIM)
    out_attn[(size_t)b * SV + idx] = sE[idx] * invL;

  // ---- emb_out + context ----
  if (tid < D) {
    const float aS = sred[0][tid] + sred[1][tid] + sred[2][tid] + sred[3][tid];
    const float eS = sred[0][D + tid] + sred[1][D + tid] + sred[2][D + tid] + sred[3][D + tid];
    float vp = 0.f;
    #pragma unroll
    for (int f = 0; f < 4; f++) {
      const float vf = sred[0][65 + f] + sred[1][65 + f] + sred[2][65 + f] + sred[3][65 + f];
      vp += vf * W_num[f * D + tid];
    }
    const float q  = sQS[tid][0] - wsc[128 + tid];
    const float eo = aS * invL - q;                     // acc held e*(q+val): undo q
    out_emb[(size_t)b * D + tid] = eo;
    sctx[tid] = eo + (eS + vp + (float)SV * b_num[tid] + smixq[tid]) * (1.f / (float)S);
  }
  __syncthreads();

  // ---- predictor head on wave 0 ----
  if (tid < H) {
    float hv = bp[tid];
    #pragma unroll
    for (int d = 0; d < D; d++) hv += sctx[d] * Wp[d * H + tid];
    hv = fmaxf(hv, 0.f);
    float mu = hv;
    #pragma unroll
    for (int off = 32; off; off >>= 1) mu += __shfl_xor(mu, off);
    mu *= (1.f / 64.f);
    const float dv = hv - mu;
    float vvv = dv * dv;
    #pragma unroll
    for (int off = 32; off; off >>= 1) vvv += __shfl_xor(vvv, off);
    vvv *= (1.f / 64.f);
    const float hn = dv * rsqrtf(vvv + 1e-3f) * ln_g[tid] + ln_b[tid];
    out_h[(size_t)b * H + tid] = hn;
    float s0 = hn * Ws[2 * tid], s1 = hn * Ws[2 * tid + 1];
    #pragma unroll
    for (int off = 32; off; off >>= 1) { s0 += __shfl_xor(s0, off); s1 += __shfl_xor(s1, off); }
    if (tid == 0) {
      const float mx = fmaxf(s0, s1);
      const float a0 = __expf(s0 - mx), a1 = __expf(s1 - mx);
      const float inv = 1.f / (a0 + a1);
      out_score[(size_t)b * 2]     = a0 * inv;
      out_score[(size_t)b * 2 + 1] = a1 * inv;
    }
  }
}

// ================= fallback (no-workspace) kernel: per-row GEMV =================
__global__ __launch_bounds__(BDIM) void attn_fused_gemv(
    const float* __restrict__ values, const int* __restrict__ names,
    const float* __restrict__ emb,
    const float* __restrict__ W_num, const float* __restrict__ b_num,
    const float* __restrict__ Wq,    const float* __restrict__ bq,
    const float* __restrict__ Wv,    const float* __restrict__ bv,
    const float* __restrict__ attn_scale,
    const float* __restrict__ Wp,    const float* __restrict__ bp,
    const float* __restrict__ ln_g,  const float* __restrict__ ln_b,
    const float* __restrict__ Ws,
    float* __restrict__ out_score, float* __restrict__ out_emb,
    float* __restrict__ out_attn,  float* __restrict__ out_h)
{
  __shared__ float sWnum[F * D];
  __shared__ float sbnum[D];
  __shared__ float sWq[D * D];
  __shared__ float sWv[D * D];
  __shared__ float sbv[D];
  __shared__ float sscale[D];
  __shared__ float sq[D];
  __shared__ float smixq[D];
  __shared__ float sred[4][2 * D];
  __shared__ float sredS[4];
  __shared__ float sML[2];
  __shared__ float sctx[D];
  __shared__ float sWp[D * H];

  const int b = blockIdx.x, tid = threadIdx.x, lane = tid & 63, wv = tid >> 6;

  for (int i = tid; i < F * D; i += BDIM) sWnum[i] = W_num[i];
  if (tid < D) { sbnum[tid] = b_num[tid]; sbv[tid] = bv[tid]; sscale[tid] = attn_scale[tid]; }
  for (int i = tid; i < D * D; i += BDIM) { sWq[i] = Wq[i]; sWv[i] = Wv[i]; }
  for (int i = tid; i < D * H; i += BDIM) sWp[i] = Wp[i];
  __syncthreads();

  if (tid < D) {
    const int    name = names[b * S + (S - 1)];
    const float* vr   = values + (size_t)(b * S + (S - 1)) * F;
    smixq[tid] = emb[(size_t)name * D + tid] + sbnum[tid]
               + vr[0] * sWnum[tid] + vr[1] * sWnum[D + tid]
               + vr[2] * sWnum[2 * D + tid] + vr[3] * sWnum[3 * D + tid];
  }
  __syncthreads();
  if (tid < D) {
    float a = bq[tid];
    #pragma unroll
    for (int k = 0; k < D; k++) a += smixq[k] * sWq[k * D + tid];
    sq[tid] = a;
  }
  __syncthreads();

  float msum[D], acc[D];
  #pragma unroll
  for (int k = 0; k < D; k++) { msum[k] = 0.f; acc[k] = 0.f; }
  float mloc = -INFINITY, lloc = 0.f;
  float sc0 = 0.f, sc1 = 0.f;
  const bool has2 = (tid < SV - BDIM);

  auto row = [&](int j, float& sout) {
    const int    name = names[b * S + j];
    const float4 v4   = *reinterpret_cast<const float4*>(values + (size_t)(b * S + j) * F);
    const float4* e4p = reinterpret_cast<const float4*>(emb + (size_t)name * D);
    float mix[D];
    #pragma unroll
    for (int c = 0; c < 8; c++) {
      const float4 e = e4p[c];
      mix[4 * c] = e.x; mix[4 * c + 1] = e.y; mix[4 * c + 2] = e.z; mix[4 * c + 3] = e.w;
    }
    #pragma unroll
    for (int k = 0; k < D; k++) {
      mix[k] += sbnum[k] + v4.x * sWnum[k] + v4.y * sWnum[D + k]
              + v4.z * sWnum[2 * D + k] + v4.w * sWnum[3 * D + k];
      msum[k] += mix[k];
    }
    float val[D];
    #pragma unroll
    for (int k = 0; k < D; k++) val[k] = sbv[k];
    for (int m = 0; m < D; m++) {
      const float mv = mix[m];
      #pragma unroll
      for (int k = 0; k < D; k++) val[k] += mv * sWv[m * D + k];
    }
    float s = 0.f;
    #pragma unroll
    for (int k = 0; k < D; k++) s += sscale[k] * fast_tanh(sq[k] + val[k]);
    sout = s;
    float w;
    if (s > mloc) {
      const float sf = __expf(mloc - s);
      lloc *= sf;
      #pragma unroll
      for (int k = 0; k < D; k++) acc[k] *= sf;
      mloc = s; w = 1.f;
    } else {
      w = __expf(s - mloc);
    }
    lloc += w;
    #pragma unroll
    for (int k = 0; k < D; k++) acc[k] += w * val[k];
  };

  row(tid, sc0);
  if (has2) row(tid + BDIM, sc1);

  float mw = mloc;
  #pragma unroll
  for (int off = 32; off; off >>= 1) mw = fmaxf(mw, __shfl_xor(mw, off));
  if (lane == 0) sredS[wv] = mw;
  __syncthreads();
  if (tid == 0) sML[0] = fmaxf(fmaxf(sredS[0], sredS[1]), fmaxf(sredS[2], sredS[3]));
  __syncthreads();
  const float M = sML[0];
  {
    const float adj = __expf(mloc - M);
    lloc *= adj;
    #pragma unroll
    for (int k = 0; k < D; k++) acc[k] *= adj;
  }
  float lw = lloc;
  #pragma unroll
  for (int off = 32; off; off >>= 1) lw += __shfl_xor(lw, off);
  if (lane == 0) sredS[wv] = lw;
  #pragma unroll
  for (int k = 0; k < D; k++) {
    float a = acc[k], mm = msum[k];
    #pragma unroll
    for (int off = 32; off; off >>= 1) { a += __shfl_xor(a, off); mm += __shfl_xor(mm, off); }
    if (lane == 0) { sred[wv][k] = a; sred[wv][D + k] = mm; }
  }
  __syncthreads();
  if (tid == 0) sML[1] = sredS[0] + sredS[1] + sredS[2] + sredS[3];
  __syncthreads();
  const float L = sML[1], invL = 1.f / L;

  out_attn[(size_t)b * SV + tid] = __expf(sc0 - M) * invL;
  if (has2) out_attn[(size_t)b * SV + tid + BDIM] = __expf(sc1 - M) * invL;

  if (tid < D) {
    const float a  = sred[0][tid] + sred[1][tid] + sred[2][tid] + sred[3][tid];
    const float mm = sred[0][D + tid] + sred[1][D + tid] + sred[2][D + tid] + sred[3][D + tid];
    const float eo = a * invL;
    out_emb[(size_t)b * D + tid] = eo;
    sctx[tid] = eo + (mm + smixq[tid]) * (1.f / (float)S);
  }
  __syncthreads();

  if (tid < H) {
    float hv = bp[tid];
    #pragma unroll
    for (int d = 0; d < D; d++) hv += sctx[d] * sWp[d * H + tid];
    hv = fmaxf(hv, 0.f);
    float mu = hv;
    #pragma unroll
    for (int off = 32; off; off >>= 1) mu += __shfl_xor(mu, off);
    mu *= (1.f / 64.f);
    const float dv = hv - mu;
    float vv = dv * dv;
    #pragma unroll
    for (int off = 32; off; off >>= 1) vv += __shfl_xor(vv, off);
    vv *= (1.f / 64.f);
    const float hn = dv * rsqrtf(vv + 1e-3f) * ln_g[tid] + ln_b[tid];
    out_h[(size_t)b * H + tid] = hn;
    float s0 = hn * Ws[2 * tid], s1 = hn * Ws[2 * tid + 1];
    #pragma unroll
    for (int off = 32; off; off >>= 1) { s0 += __shfl_xor(s0, off); s1 += __shfl_xor(s1, off); }
    if (tid == 0) {
      const float mx = fmaxf(s0, s1);
      const float a0 = __expf(s0 - mx), a1 = __expf(s1 - mx);
      const float inv = 1.f / (a0 + a1);
      out_score[(size_t)b * 2]     = a0 * inv;
      out_score[(size_t)b * 2 + 1] = a1 * inv;
    }
  }
}

extern "C" void kernel_launch(void* const* d_in, const int* in_sizes, int n_in,
                              void* d_out, int out_size, void* d_ws, size_t ws_size,
                              hipStream_t stream) {
  const float* values = (const float*)d_in[0];
  const int*   names  = (const int*)d_in[1];
  const float* emb    = (const float*)d_in[2];
  const float* W_num  = (const float*)d_in[3];
  const float* b_num  = (const float*)d_in[4];
  const float* Wq     = (const float*)d_in[5];
  const float* bq     = (const float*)d_in[6];
  const float* Wv     = (const float*)d_in[7];
  const float* bv     = (const float*)d_in[8];
  const float* scal   = (const float*)d_in[9];
  const float* Wp     = (const float*)d_in[10];
  const float* bp     = (const float*)d_in[11];
  const float* ln_g   = (const float*)d_in[12];
  const float* ln_b   = (const float*)d_in[13];
  const float* Ws     = (const float*)d_in[14];

  float* out      = (float*)d_out;
  float* o_score  = out;
  float* o_emb    = o_score + (size_t)Bsz * 2;
  float* o_attn   = o_emb   + (size_t)Bsz * D;
  float* o_h      = o_attn  + (size_t)Bsz * SV;

  const size_t need = TAB_BYTES + 256 * sizeof(float);
  if (ws_size >= need) {
    __hip_bfloat16* T = (__hip_bfloat16*)d_ws;
    float* wsc = (float*)((char*)d_ws + TAB_BYTES);
    hipLaunchKernelGGL(build_tab, dim3((VOCAB + 7) / 8 + 1), dim3(BDIM), 0, stream,
                       emb, Wv, W_num, b_num, bv, T, wsc);
    hipLaunchKernelGGL(attn_main, dim3(Bsz), dim3(BDIM), 0, stream,
                       values, names, T, wsc, emb, W_num, b_num, Wq, bq, scal,
                       Wp, bp, ln_g, ln_b, Ws, o_score, o_emb, o_attn, o_h);
  } else {
    hipLaunchKernelGGL(attn_fused_gemv, dim3(Bsz), dim3(BDIM), 0, stream,
                       values, names, emb, W_num, b_num, Wq, bq, Wv, bv, scal,
                       Wp, bp, ln_g, ln_b, Ws, o_score, o_emb, o_attn, o_h);
  }
}